// Round 1
// baseline (137.012 us; speedup 1.0000x reference)
//
#include <hip/hip_runtime.h>
#include <hip/hip_bf16.h>
#include <cstdint>

#define N_IDE 4096
#define M_U   16384
#define D_DIM 256
#define EPSF  1e-12f
#define INV_M (1.0f / 16384.0f)

#define CGC   256                 // columns per column-group tile
#define BK    32                  // K per step
#define SB_ELEMS (CGC * BK)       // 8192 f16 = 16 KB per buffer
#define NBUF  4                   // B ring buffer depth (depth-3 prefetch)
#define NSTEP 64                  // 8 column-groups x 8 K-steps

typedef _Float16 f16x8 __attribute__((ext_vector_type(8)));
typedef float    f32x4 __attribute__((ext_vector_type(4)));

// ---- async global->LDS 16B copy. LDS dest = wave-uniform base + lane*16. ----
__device__ __forceinline__ void gll16(const void* g, void* l) {
  __builtin_amdgcn_global_load_lds(
      (const __attribute__((address_space(1))) void*)(uintptr_t)g,
      (__attribute__((address_space(3))) void*)(uint32_t)(uintptr_t)l,
      16, 0, 0);
}

__device__ __forceinline__ unsigned short f2h_bits(float f) {
  _Float16 h = (_Float16)f;
  return __builtin_bit_cast(unsigned short, h);
}

// ---- Kernel 1: fp32 -> f16 convert + row squared-norms (one wave per row) ----
__global__ __launch_bounds__(256) void k_conv(const float* __restrict__ ide,
                                              const float* __restrict__ u,
                                              unsigned short* __restrict__ Ah,
                                              unsigned short* __restrict__ Bh,
                                              float* __restrict__ x2,
                                              float* __restrict__ y2) {
  int gw = (blockIdx.x * 256 + threadIdx.x) >> 6;
  int l  = threadIdx.x & 63;
  const float4* src;
  ushort4* dst;
  float* nrm;
  if (gw < N_IDE) {
    src = (const float4*)(ide + (size_t)gw * D_DIM);
    dst = (ushort4*)(Ah + (size_t)gw * D_DIM);
    nrm = x2 + gw;
  } else {
    int r = gw - N_IDE;
    src = (const float4*)(u + (size_t)r * D_DIM);
    dst = (ushort4*)(Bh + (size_t)r * D_DIM);
    nrm = y2 + r;
  }
  float4 v = src[l];
  float s = v.x * v.x + v.y * v.y + v.z * v.z + v.w * v.w;
  ushort4 o;
  o.x = f2h_bits(v.x); o.y = f2h_bits(v.y);
  o.z = f2h_bits(v.z); o.w = f2h_bits(v.w);
  dst[l] = o;
#pragma unroll
  for (int m = 1; m <= 32; m <<= 1) s += __shfl_xor(s, m, 64);
  if (l == 0) *nrm = s;
}

// ---- Kernel 2: persistent-A MFMA GEMM, 512 threads (8 waves, 2/SIMD) ----
// grid (8, 32): by = 128-row group; bx picks 8 of 64 column-groups (2048 cols).
// LDS: A 128x256 f16 (64KB, swizzled, staged once)
//    + B ring buffer NBUF=4 x (256 cols x 32 K) f16 (4x16KB)
//    + sY: y2 slice for this block's 8 column-groups (8KB)   => 136 KB total
// Pipeline: depth-3 prefetch via global_load_lds; per step:
//   issue stage(s+3); ds_read frags from buf s&3; 16 MFMA;
//   s_waitcnt vmcnt(4) (stage(s+1) done, s+2/s+3 STAY IN FLIGHT); raw s_barrier.
// No compiler-tracked global loads in the loop, so the vmcnt count is exact.
// B read-side XOR swizzle (chunk = lhi ^ ((row>>1)&3)) kills the 8-way
// bank conflict of the 64B-pitch layout; source is pre-swizzled at staging.
__global__ __launch_bounds__(512, 2) void k_gemm(const unsigned short* __restrict__ Ah,
                                                 const unsigned short* __restrict__ Bh,
                                                 const float* __restrict__ x2,
                                                 const float* __restrict__ y2,
                                                 float* __restrict__ partial) {
  __shared__ __align__(16) unsigned short sA[128 * 256];        // 64 KB
  __shared__ __align__(16) unsigned short sB[NBUF * SB_ELEMS];  // 64 KB
  __shared__ __align__(16) float sY[8 * CGC];                   // 8 KB

  const int t    = threadIdx.x;
  const int w    = t >> 6;
  const int l    = t & 63;
  const int wm   = w >> 2, wn = w & 3;   // 2x4 wave grid; wave tile 64x64
  const int lrow = l & 15;
  const int lhi  = l >> 4;
  const int bx   = blockIdx.x;           // 0..7
  const int by   = blockIdx.y;           // 0..31
  const int pchB = lhi ^ ((lrow >> 1) & 3);  // B read swizzle (lane-const)

  // x2 for this wave's rows, registers for the whole kernel
  float4 x2v[4];
#pragma unroll
  for (int mi = 0; mi < 4; ++mi)
    x2v[mi] = *(const float4*)&x2[by * 128 + wm * 64 + mi * 16 + lhi * 4];

  // ---- stage A (128 rows x 256 K), XOR-swizzled in 16B chunks ----
#pragma unroll
  for (int i = 0; i < 8; ++i) {
    int L = i * 512 + t;                 // chunk id 0..4095
    int row = L >> 5;
    int p = L & 31;
    int c = (p & 24) | ((p & 7) ^ (row & 7));
    gll16(Ah + (size_t)(by * 128 + row) * D_DIM + c * 8,
          sA + (size_t)(i * 512 + w * 64) * 8);
  }
  // ---- stage y2 slice: wave w loads column-group (w*8+bx), 256 floats ----
  gll16(y2 + (size_t)(w * 8 + bx) * CGC + l * 4, sY + w * CGC + l * 4);

  // per-thread constant staging offsets for B (source pre-swizzled)
  const int r0 = t >> 2,        r1 = (512 + t) >> 2;
  const int c0 = (t & 3) ^ ((r0 >> 1) & 3);
  const int c1 = (t & 3) ^ ((r1 >> 1) & 3);
  const size_t soff0 = (size_t)r0 * D_DIM + c0 * 8;
  const size_t soff1 = (size_t)r1 * D_DIM + c1 * 8;

  auto stageB = [&](int s) {
    const unsigned short* src =
        Bh + (size_t)(((s >> 3) * 8 + bx) * CGC) * D_DIM + (s & 7) * BK;
    unsigned short* dstb = sB + (size_t)(s & 3) * SB_ELEMS;
    gll16(src + soff0, dstb + (size_t)(w * 64) * 8);
    gll16(src + soff1, dstb + (size_t)(512 + w * 64) * 8);
  };

  stageB(0); stageB(1); stageB(2);
  // A, sY, x2, B0 complete; B1,B2 stay in flight (in-order drain)
  asm volatile("s_waitcnt vmcnt(4)" ::: "memory");
  asm volatile("s_barrier" ::: "memory");

  f32x4 acc[4][4];
#pragma unroll
  for (int mi = 0; mi < 4; ++mi)
#pragma unroll
    for (int nj = 0; nj < 4; ++nj)
      acc[mi][nj] = (f32x4){0.f, 0.f, 0.f, 0.f};

  float racc[4][4];
#pragma unroll
  for (int mi = 0; mi < 4; ++mi)
#pragma unroll
    for (int rr = 0; rr < 4; ++rr)
      racc[mi][rr] = 0.f;

  for (int s = 0; s < NSTEP; ++s) {
    const int kt = s & 7;
    if (s + 3 < NSTEP) stageB(s + 3);

    // A fragments: logical chunk kt*4+lhi, physical = swizzled
    const int lc = kt * 4 + lhi;
    const int pc = (lc & 24) | ((lc & 7) ^ (lrow & 7));
    f16x8 af[4];
#pragma unroll
    for (int mi = 0; mi < 4; ++mi)
      af[mi] = *(const f16x8*)(sA + (size_t)(wm * 64 + mi * 16 + lrow) * 256 + pc * 8);

    const unsigned short* bbuf = sB + (size_t)(s & 3) * SB_ELEMS;
    f16x8 bf[4];
#pragma unroll
    for (int nj = 0; nj < 4; ++nj)
      bf[nj] = *(const f16x8*)(bbuf + (size_t)(wn * 64 + nj * 16 + lrow) * BK + pchB * 8);

#pragma unroll
    for (int mi = 0; mi < 4; ++mi)
#pragma unroll
      for (int nj = 0; nj < 4; ++nj)
        acc[mi][nj] = __builtin_amdgcn_mfma_f32_16x16x32_f16(af[mi], bf[nj],
                                                             acc[mi][nj], 0, 0, 0);

    if (kt == 7) {
      // epilogue: dist + per-row partial sums, registers + sY (lgkm only;
      // overlaps the in-flight stages). Then reset acc for next cg.
      const int cgl = s >> 3;
      float yv[4];
#pragma unroll
      for (int ni = 0; ni < 4; ++ni)
        yv[ni] = sY[cgl * CGC + wn * 64 + ni * 16 + lrow];
#pragma unroll
      for (int mi = 0; mi < 4; ++mi) {
        float xr[4] = {x2v[mi].x, x2v[mi].y, x2v[mi].z, x2v[mi].w};
#pragma unroll
        for (int rr = 0; rr < 4; ++rr) {
          float ssum = 0.f;
#pragma unroll
          for (int ni = 0; ni < 4; ++ni) {
            float d2 = xr[rr] + yv[ni] - 2.0f * acc[mi][ni][rr];
            d2 = fmaxf(d2, 0.0f);
            ssum += __builtin_amdgcn_sqrtf(d2 + EPSF);
          }
          racc[mi][rr] += ssum;
        }
      }
#pragma unroll
      for (int mi = 0; mi < 4; ++mi)
#pragma unroll
        for (int nj = 0; nj < 4; ++nj)
          acc[mi][nj] = (f32x4){0.f, 0.f, 0.f, 0.f};
    }

    // counted wait: stage(s+1) done; stage(s+2), stage(s+3) remain in flight
    if (s < NSTEP - 3)       asm volatile("s_waitcnt vmcnt(4)" ::: "memory");
    else if (s == NSTEP - 3) asm volatile("s_waitcnt vmcnt(2)" ::: "memory");
    else                     asm volatile("s_waitcnt vmcnt(0)" ::: "memory");
    asm volatile("s_barrier" ::: "memory");
  }

  // ---- final reduce over lrow lanes, direct per-wave store (no rowacc LDS) ----
  const int slot = bx * 4 + wn;
#pragma unroll
  for (int mi = 0; mi < 4; ++mi) {
    float rv[4];
#pragma unroll
    for (int rr = 0; rr < 4; ++rr) {
      float v = racc[mi][rr];
      v += __shfl_xor(v, 1, 64);
      v += __shfl_xor(v, 2, 64);
      v += __shfl_xor(v, 4, 64);
      v += __shfl_xor(v, 8, 64);
      rv[rr] = v;
    }
    if (lrow == 0) {
      float4 o = make_float4(rv[0], rv[1], rv[2], rv[3]);
      *(float4*)&partial[(size_t)slot * N_IDE + by * 128 + wm * 64 + mi * 16 + lhi * 4] = o;
    }
  }
}

// ---- Kernel 3: loss = sum_{i,j} sqrt(((d_i-d_j))^2 + eps), d from partials ----
__global__ __launch_bounds__(256) void k_loss(const float* __restrict__ partial,
                                              float* __restrict__ out) {
  __shared__ float sd[N_IDE];
  __shared__ float wsum[4];
  int t = threadIdx.x;
  for (int k = t; k < N_IDE; k += 256) {
    float s = 0.f;
#pragma unroll
    for (int b = 0; b < 32; ++b) s += partial[(size_t)b * N_IDE + k];
    sd[k] = s;
  }
  __syncthreads();
  int tid = blockIdx.x * 256 + t;   // 65536 threads: 16 per i
  int i   = tid >> 4;
  int jl  = tid & 15;
  float di = sd[i];
  float s  = 0.f;
  for (int k = 0; k < 256; ++k) {
    float diff = (di - sd[jl + k * 16]) * INV_M;
    s += __builtin_amdgcn_sqrtf(diff * diff + EPSF);
  }
#pragma unroll
  for (int m = 1; m <= 32; m <<= 1) s += __shfl_xor(s, m, 64);
  if ((t & 63) == 0) wsum[t >> 6] = s;
  __syncthreads();
  if (t == 0) atomicAdd(out, wsum[0] + wsum[1] + wsum[2] + wsum[3]);
}

extern "C" void kernel_launch(void* const* d_in, const int* in_sizes, int n_in,
                              void* d_out, int out_size, void* d_ws, size_t ws_size,
                              hipStream_t stream) {
  (void)in_sizes; (void)n_in; (void)out_size; (void)ws_size;
  const float* ide = (const float*)d_in[0];
  const float* u   = (const float*)d_in[1];
  float* out = (float*)d_out;

  char* ws = (char*)d_ws;
  size_t off = 0;
  unsigned short* Ah = (unsigned short*)(ws + off); off += (size_t)N_IDE * D_DIM * 2;  // 2 MB
  unsigned short* Bh = (unsigned short*)(ws + off); off += (size_t)M_U  * D_DIM * 2;   // 8 MB
  float* x2      = (float*)(ws + off); off += (size_t)N_IDE * 4;
  float* y2      = (float*)(ws + off); off += (size_t)M_U * 4;
  float* partial = (float*)(ws + off); off += (size_t)32 * N_IDE * 4;                  // 512 KB

  hipMemsetAsync(d_out, 0, sizeof(float), stream);
  k_conv<<<(N_IDE + M_U) / 4, 256, 0, stream>>>(ide, u, Ah, Bh, x2, y2);
  k_gemm<<<dim3(8, 32), 512, 0, stream>>>(Ah, Bh, x2, y2, partial);
  k_loss<<<256, 256, 0, stream>>>(partial, out);
}